// Round 6
// baseline (107.988 us; speedup 1.0000x reference)
//
#include <hip/hip_runtime.h>
#include <math.h>

// HiddenTreeMarkovModel upward recursion.
// T_TREES=128, BR=2, DEPTH=11, C=8, L=2, M=256, G=4.
// Grid = 256 blocks (one resident block per CU, single pass):
//   block = (tree t, g-pair), t = blockIdx.x>>1, g0 = 2*(blockIdx.x&1).
// 512 threads = 8 waves = 2 waves/SIMD; __launch_bounds__(512,2) -> 256-VGPR
// cap so the register A-matrices (128 VGPRs) never spill (round-3 lesson:
// VGPR=64 cap caused 105MB/125MB scratch traffic; round-5 fixed it but its
// grid=512 ran two sequential passes per CU).
//
// Stage 1: fused levels 11,10,9 (7-node subtree in registers), gi-loop over
//          the block's two g's.
// Stage 2: both gi's processed concurrently (thread=(mygi,q)); two tree
//          levels fused per barrier: 9->7->5->3, then 3->0 in one thread.
//          4 barriers instead of 9.
// Level offsets: offs[l] = 128*(2^l - 1); tree t owns [offs[l]+t*2^l, +2^l).

#define NTHREADS 512
#define NSTR 17   // per-node floats in beta buffers: 2 gi x 8 c + 1 pad (odd)

__global__ __launch_bounds__(NTHREADS, 2) void htmm_kernel(
    const float* __restrict__ lA,   // (C,C,L,G)  c*64 + d*8 + p*4 + g
    const float* __restrict__ lB,   // (C,M,G)    c*1024 + m*4 + g
    const float* __restrict__ lPi,  // (C,L,G)    c*8 + p*4 + g
    const float* __restrict__ lSP,  // (L,G)      p*4 + g
    const int* __restrict__ pos,
    const int* __restrict__ xx,
    float* __restrict__ out)        // (128,4)
{
    __shared__ __align__(16) float sBm[2 * 256 * 8];  // [gg][m][c]
    __shared__ __align__(16) float sA[256];           // [gg][pv][c][d]
    __shared__ __align__(16) float sPi[32];           // [gg][pv][c]
    __shared__ float sSP[4];                          // [gg*2+pv]
    __shared__ float sInv[16];                        // [gg*8+c]
    __shared__ float buf0[512 * NSTR];                // levels 9, 5
    __shared__ float buf1[128 * NSTR];                // levels 7, 3
    __shared__ double sLL[2];

    const int tid = threadIdx.x;
    const int t  = blockIdx.x >> 1;
    const int g0 = (blockIdx.x & 1) << 1;

    if (tid < 2) sLL[tid] = 0.0;

    // ---------- softmax tables (our 2 g's) ----------
    // Bm exp pass: 4096 elems, layout [gg][m][c]
#pragma unroll
    for (int k = 0; k < 8; ++k) {
        int w = tid + k * NTHREADS;
        int gg = w >> 11, m = (w >> 3) & 255, c = w & 7;
        sBm[w] = expf(lB[c * 1024 + m * 4 + g0 + gg]);
    }
    __syncthreads();

    if (tid < 256) {
        // row sums over m per (gg,c): 16 rows x 16 threads, staggered
        int r = tid >> 4, seg = tid & 15;       // r = gg*8 + c
        int gg = r >> 3, c = r & 7;
        float s = 0.f;
#pragma unroll
        for (int i = 0; i < 16; ++i)
            s += sBm[(gg << 11) + (((seg * 16 + ((i + seg) & 15))) << 3) + c];
#pragma unroll
        for (int o = 8; o >= 1; o >>= 1) s += __shfl_xor(s, o, 64);
        if (seg == 0) sInv[r] = 1.0f / s;
    } else if (tid < 288) {
        // A softmax over c, per (d,pp,gg)
        int w = tid - 256;
        int d = w >> 2, pp = (w >> 1) & 1, gg = w & 1;
        float e[8]; float s = 0.f;
#pragma unroll
        for (int c = 0; c < 8; ++c) { e[c] = expf(lA[c * 64 + d * 8 + pp * 4 + g0 + gg]); s += e[c]; }
        float inv = 1.f / s;
#pragma unroll
        for (int c = 0; c < 8; ++c) sA[gg * 128 + pp * 64 + c * 8 + d] = e[c] * inv;
    } else if (tid < 292) {
        int w = tid - 288; int pp = w >> 1, gg = w & 1;
        float e[8]; float s = 0.f;
#pragma unroll
        for (int c = 0; c < 8; ++c) { e[c] = expf(lPi[c * 8 + pp * 4 + g0 + gg]); s += e[c]; }
        float inv = 1.f / s;
#pragma unroll
        for (int c = 0; c < 8; ++c) sPi[gg * 16 + pp * 8 + c] = e[c] * inv;
    } else if (tid < 294) {
        int gg = tid - 292;
        float e0 = expf(lSP[g0 + gg]), e1 = expf(lSP[4 + g0 + gg]);
        float inv = 1.f / (e0 + e1);
        sSP[gg * 2] = e0 * inv; sSP[gg * 2 + 1] = e1 * inv;
    }
    __syncthreads();

    // Bm normalize
#pragma unroll
    for (int k = 0; k < 8; ++k) {
        int w = tid + k * NTHREADS;
        sBm[w] *= sInv[((w >> 11) << 3) + (w & 7)];
    }
    __syncthreads();

    // ---------- register tables (reloaded per phase) ----------
    float A0r[64], A1r[64], Pi0r[8], Pi1r[8];
    float SP0, SP1;
    auto loadTabs = [&](int gg) {
        const float4* a0 = (const float4*)(sA + gg * 128);
        const float4* a1 = (const float4*)(sA + gg * 128 + 64);
#pragma unroll
        for (int q = 0; q < 16; ++q) {
            float4 v0 = a0[q];
            A0r[4*q] = v0.x; A0r[4*q+1] = v0.y; A0r[4*q+2] = v0.z; A0r[4*q+3] = v0.w;
            float4 v1 = a1[q];
            A1r[4*q] = v1.x; A1r[4*q+1] = v1.y; A1r[4*q+2] = v1.z; A1r[4*q+3] = v1.w;
        }
#pragma unroll
        for (int c = 0; c < 8; ++c) { Pi0r[c] = sPi[gg*16 + c]; Pi1r[c] = sPi[gg*16 + 8 + c]; }
        SP0 = sSP[gg*2]; SP1 = sSP[gg*2 + 1];
    };

    // acc[c] += scale * (A_pv . b), register-only with per-lane pv select
    auto matvec_acc = [&](const float* b, int pv, float scale, float* acc) {
        float s0[8], s1[8];
#pragma unroll
        for (int c = 0; c < 8; ++c) { s0[c] = 0.f; s1[c] = 0.f; }
#pragma unroll
        for (int c = 0; c < 8; ++c) {
#pragma unroll
            for (int d = 0; d < 8; ++d) {
                s0[c] += A0r[(c << 3) + d] * b[d];
                s1[c] += A1r[(c << 3) + d] * b[d];
            }
        }
#pragma unroll
        for (int c = 0; c < 8; ++c) acc[c] += scale * (pv ? s1[c] : s0[c]);
    };

    auto bm_gather = [&](int gg, int xv, float* bm) {
        const float4 v0 = *(const float4*)(sBm + (gg << 11) + (xv << 3));
        const float4 v1 = *(const float4*)(sBm + (gg << 11) + (xv << 3) + 4);
        bm[0] = v0.x; bm[1] = v0.y; bm[2] = v0.z; bm[3] = v0.w;
        bm[4] = v1.x; bm[5] = v1.y; bm[6] = v1.z; bm[7] = v1.w;
    };

    float ll0 = 0.f, ll1 = 0.f;   // log2-domain partials for g0, g0+1

    // ---------- stage 1: fused levels 11,10,9 (gi-loop) ----------
    {
        const int j = tid;   // level-9 node within tree
        const int4 pv4 = *(const int4*)(pos + 262016 + t * 2048 + 4 * j);
        const int4 xv4 = *(const int4*)(xx  + 262016 + t * 2048 + 4 * j);
        const int2 pu2 = *(const int2*)(pos + 130944 + t * 1024 + 2 * j);
        const int2 xu2 = *(const int2*)(xx  + 130944 + t * 1024 + 2 * j);
        const int xq = xx[65408 + t * 512 + j];

        for (int gg = 0; gg < 2; ++gg) {
            loadTabs(gg);
            float llacc = 0.f;
            float tq[8] = {0,0,0,0,0,0,0,0};
#pragma unroll
            for (int u = 0; u < 2; ++u) {
                float tu[8] = {0,0,0,0,0,0,0,0};
#pragma unroll
                for (int v = 0; v < 2; ++v) {
                    const int k = 2 * u + v;
                    const int pv  = (k == 0) ? pv4.x : (k == 1) ? pv4.y : (k == 2) ? pv4.z : pv4.w;
                    const int xvv = (k == 0) ? xv4.x : (k == 1) ? xv4.y : (k == 2) ? xv4.z : xv4.w;
                    float bm[8]; bm_gather(gg, xvv, bm);
                    float b[8]; float nu = 0.f;
#pragma unroll
                    for (int c = 0; c < 8; ++c) {
                        b[c] = (pv ? Pi1r[c] : Pi0r[c]) * bm[c];
                        nu += b[c];
                    }
                    llacc += __log2f(nu);
                    matvec_acc(b, pv, (pv ? SP1 : SP0) / nu, tu);
                }
                const int pu = u ? pu2.y : pu2.x;
                const int xu = u ? xu2.y : xu2.x;
                float bm[8]; bm_gather(gg, xu, bm);
                float bu[8]; float nuu = 0.f;
#pragma unroll
                for (int c = 0; c < 8; ++c) { bu[c] = tu[c] * bm[c]; nuu += bu[c]; }
                llacc += __log2f(nuu);
                matvec_acc(bu, pu, (pu ? SP1 : SP0) / nuu, tq);
            }
            float bm[8]; bm_gather(gg, xq, bm);
            float bq[8]; float nuq = 0.f;
#pragma unroll
            for (int c = 0; c < 8; ++c) { bq[c] = tq[c] * bm[c]; nuq += bq[c]; }
            llacc += __log2f(nuq);
            const float inv = 1.f / nuq;
#pragma unroll
            for (int c = 0; c < 8; ++c) buf0[j * NSTR + (gg << 3) + c] = bq[c] * inv;
            if (gg == 0) ll0 += llacc; else ll1 += llacc;
        }
    }
    __syncthreads();

    // ---------- stage 2: both gi concurrent, 2 levels per barrier ----------
    const int mygi = tid >> 8;      // wave-uniform
    const int q    = tid & 255;
    loadTabs(mygi);
    float llt = 0.f;                // own-gi stage-2 partial (log2)

    // children level L in bin_ (within-tree idx 4q+i) -> parents level L-2 in bout_[q]
    auto step2 = [&](const float* bin_, float* bout_, int L) {
        const int nQ = 1 << (L - 2);
        if (q < nQ) {
            const int offC = 128 * ((1 << L) - 1) + t * (1 << L);
            const int offM = 128 * ((1 << (L - 1)) - 1) + t * (1 << (L - 1));
            const int offP = 128 * ((1 << (L - 2)) - 1) + t * (1 << (L - 2));
            const int4 pc = *(const int4*)(pos + offC + 4 * q);
            const int2 pm = *(const int2*)(pos + offM + 2 * q);
            const int2 xm = *(const int2*)(xx  + offM + 2 * q);
            const int xp  = xx[offP + q];
            float tq8[8] = {0,0,0,0,0,0,0,0};
#pragma unroll
            for (int u = 0; u < 2; ++u) {
                float tu8[8] = {0,0,0,0,0,0,0,0};
#pragma unroll
                for (int v = 0; v < 2; ++v) {
                    const int i = 2 * u + v;
                    const int pvc = (i == 0) ? pc.x : (i == 1) ? pc.y : (i == 2) ? pc.z : pc.w;
                    const float* bp = &bin_[(4 * q + i) * NSTR + (mygi << 3)];
                    float b[8];
#pragma unroll
                    for (int d = 0; d < 8; ++d) b[d] = bp[d];
                    matvec_acc(b, pvc, pvc ? SP1 : SP0, tu8);
                }
                const int pmu = u ? pm.y : pm.x;
                const int xmu = u ? xm.y : xm.x;
                float bm[8]; bm_gather(mygi, xmu, bm);
                float bu[8]; float nu = 0.f;
#pragma unroll
                for (int c = 0; c < 8; ++c) { bu[c] = tu8[c] * bm[c]; nu += bu[c]; }
                llt += __log2f(nu);
                matvec_acc(bu, pmu, (pmu ? SP1 : SP0) / nu, tq8);
            }
            float bm[8]; bm_gather(mygi, xp, bm);
            float bp8[8]; float nu = 0.f;
#pragma unroll
            for (int c = 0; c < 8; ++c) { bp8[c] = tq8[c] * bm[c]; nu += bp8[c]; }
            llt += __log2f(nu);
            const float inv = 1.f / nu;
#pragma unroll
            for (int c = 0; c < 8; ++c) bout_[q * NSTR + (mygi << 3) + c] = bp8[c] * inv;
        }
        __syncthreads();
    };

    step2(buf0, buf1, 9);   // level 9 -> 7   (q < 128)
    step2(buf1, buf0, 7);   // level 7 -> 5   (q < 32)
    step2(buf0, buf1, 5);   // level 5 -> 3   (q < 8)

    // final: levels 3 -> 2 -> 1 -> 0 in one thread per gi (q == 0)
    if (q == 0) {
        const int off3 = 896 + t * 8;
        const int off2 = 384 + t * 4;
        const int off1 = 128 + t * 2;
        const int4 p3a = *(const int4*)(pos + off3);
        const int4 p3b = *(const int4*)(pos + off3 + 4);
        const int4 p2  = *(const int4*)(pos + off2);
        const int4 x2  = *(const int4*)(xx  + off2);
        const int2 p1  = *(const int2*)(pos + off1);
        const int2 x1  = *(const int2*)(xx  + off1);
        const int x0   = xx[t];

        float tl1a[8] = {0,0,0,0,0,0,0,0};
        float tl1b[8] = {0,0,0,0,0,0,0,0};
#pragma unroll
        for (int w = 0; w < 4; ++w) {
            float tw[8] = {0,0,0,0,0,0,0,0};
#pragma unroll
            for (int v = 0; v < 2; ++v) {
                const int i = 2 * w + v;
                const int pvc = (i == 0) ? p3a.x : (i == 1) ? p3a.y : (i == 2) ? p3a.z :
                                (i == 3) ? p3a.w : (i == 4) ? p3b.x : (i == 5) ? p3b.y :
                                (i == 6) ? p3b.z : p3b.w;
                const float* bp = &buf1[i * NSTR + (mygi << 3)];
                float b[8];
#pragma unroll
                for (int d = 0; d < 8; ++d) b[d] = bp[d];
                matvec_acc(b, pvc, pvc ? SP1 : SP0, tw);
            }
            const int pw = (w == 0) ? p2.x : (w == 1) ? p2.y : (w == 2) ? p2.z : p2.w;
            const int xw = (w == 0) ? x2.x : (w == 1) ? x2.y : (w == 2) ? x2.z : x2.w;
            float bm[8]; bm_gather(mygi, xw, bm);
            float bw[8]; float nu = 0.f;
#pragma unroll
            for (int c = 0; c < 8; ++c) { bw[c] = tw[c] * bm[c]; nu += bw[c]; }
            llt += __log2f(nu);
            matvec_acc(bw, pw, (pw ? SP1 : SP0) / nu, (w < 2) ? tl1a : tl1b);
        }
        float tl0[8] = {0,0,0,0,0,0,0,0};
#pragma unroll
        for (int u = 0; u < 2; ++u) {
            const float* tsrc = u ? tl1b : tl1a;
            const int pu = u ? p1.y : p1.x;
            const int xu = u ? x1.y : x1.x;
            float bm[8]; bm_gather(mygi, xu, bm);
            float bu[8]; float nu = 0.f;
#pragma unroll
            for (int c = 0; c < 8; ++c) { bu[c] = tsrc[c] * bm[c]; nu += bu[c]; }
            llt += __log2f(nu);
            matvec_acc(bu, pu, (pu ? SP1 : SP0) / nu, tl0);
        }
        float bm[8]; bm_gather(mygi, x0, bm);
        float nu = 0.f;
#pragma unroll
        for (int c = 0; c < 8; ++c) nu += tl0[c] * bm[c];
        llt += __log2f(nu);
    }
    if (mygi) ll1 += llt; else ll0 += llt;

    // ---------- final log-likelihood reduction ----------
    float f0 = ll0 * 0.69314718055994530942f;   // log2 -> ln
    float f1 = ll1 * 0.69314718055994530942f;
#pragma unroll
    for (int o = 32; o >= 1; o >>= 1) {
        f0 += __shfl_xor(f0, o, 64);
        f1 += __shfl_xor(f1, o, 64);
    }
    if ((tid & 63) == 0) {
        atomicAdd(&sLL[0], (double)f0);
        atomicAdd(&sLL[1], (double)f1);
    }
    __syncthreads();
    if (tid < 2) out[(t << 2) + g0 + tid] = (float)sLL[tid];
}

extern "C" void kernel_launch(void* const* d_in, const int* in_sizes, int n_in,
                              void* d_out, int out_size, void* d_ws, size_t ws_size,
                              hipStream_t stream) {
    const float* lA  = (const float*)d_in[0];
    const float* lB  = (const float*)d_in[1];
    const float* lPi = (const float*)d_in[2];
    const float* lSP = (const float*)d_in[3];
    const int*   pos = (const int*)d_in[4];
    const int*   xv  = (const int*)d_in[5];
    float* out = (float*)d_out;
    htmm_kernel<<<256, NTHREADS, 0, stream>>>(lA, lB, lPi, lSP, pos, xv, out);
}

// Round 7
// 105.176 us; speedup vs baseline: 1.0267x; 1.0267x over previous
//
#include <hip/hip_runtime.h>
#include <math.h>

// HiddenTreeMarkovModel upward recursion.
// T_TREES=128, BR=2, DEPTH=11, C=8, L=2, M=256, G=4.
// Grid = 256 blocks (one resident block per CU, single pass):
//   block = (tree t, g-pair), t = blockIdx.x>>1, g0 = 2*(blockIdx.x&1).
// 512 threads = 8 waves = 2 waves/SIMD.
//
// Round-7 fix: __launch_bounds__(512,2) only sets MIN waves/EU (range [2,8]);
// the backend still targeted 4 waves/EU -> 128-VGPR cap -> spilled the
// ~210-reg working set (r6 counters: VGPR=128, WRITE_SIZE 28.5MB of scratch
// vs 2KB of real output). amdgpu_waves_per_eu(2,2) pins min=max=2 -> exact
// 256-VGPR budget, no spill. Runtime occupancy unchanged (1 block/CU).
// Math identical to round 6 (passed, absmax 0.0).
//
// Stage 1: fused levels 11,10,9 (7-node subtree in registers), gg-loop
//          (not unrolled: keeps one g's tables live at a time).
// Stage 2: both gi's concurrent (thread=(mygi,q)); two tree levels fused per
//          barrier: 9->7->5->3, then 3->0 in one thread. 4 barriers total.
// Level offsets: offs[l] = 128*(2^l - 1); tree t owns [offs[l]+t*2^l, +2^l).

#define NTHREADS 512
#define NSTR 17   // per-node floats in beta buffers: 2 gi x 8 c + 1 pad (odd)

__global__ __launch_bounds__(NTHREADS)
__attribute__((amdgpu_waves_per_eu(2, 2)))
void htmm_kernel(
    const float* __restrict__ lA,   // (C,C,L,G)  c*64 + d*8 + p*4 + g
    const float* __restrict__ lB,   // (C,M,G)    c*1024 + m*4 + g
    const float* __restrict__ lPi,  // (C,L,G)    c*8 + p*4 + g
    const float* __restrict__ lSP,  // (L,G)      p*4 + g
    const int* __restrict__ pos,
    const int* __restrict__ xx,
    float* __restrict__ out)        // (128,4)
{
    __shared__ __align__(16) float sBm[2 * 256 * 8];  // [gg][m][c]
    __shared__ __align__(16) float sA[256];           // [gg][pv][c][d]
    __shared__ __align__(16) float sPi[32];           // [gg][pv][c]
    __shared__ float sSP[4];                          // [gg*2+pv]
    __shared__ float sInv[16];                        // [gg*8+c]
    __shared__ float buf0[512 * NSTR];                // levels 9, 5
    __shared__ float buf1[128 * NSTR];                // levels 7, 3
    __shared__ double sLL[2];

    const int tid = threadIdx.x;
    const int t  = blockIdx.x >> 1;
    const int g0 = (blockIdx.x & 1) << 1;

    if (tid < 2) sLL[tid] = 0.0;

    // ---------- softmax tables (our 2 g's) ----------
    // Bm exp pass: 4096 elems, layout [gg][m][c]
#pragma unroll
    for (int k = 0; k < 8; ++k) {
        int w = tid + k * NTHREADS;
        int gg = w >> 11, m = (w >> 3) & 255, c = w & 7;
        sBm[w] = expf(lB[c * 1024 + m * 4 + g0 + gg]);
    }
    __syncthreads();

    if (tid < 256) {
        // row sums over m per (gg,c): 16 rows x 16 threads, staggered
        int r = tid >> 4, seg = tid & 15;       // r = gg*8 + c
        int gg = r >> 3, c = r & 7;
        float s = 0.f;
#pragma unroll
        for (int i = 0; i < 16; ++i)
            s += sBm[(gg << 11) + (((seg * 16 + ((i + seg) & 15))) << 3) + c];
#pragma unroll
        for (int o = 8; o >= 1; o >>= 1) s += __shfl_xor(s, o, 64);
        if (seg == 0) sInv[r] = 1.0f / s;
    } else if (tid < 288) {
        // A softmax over c, per (d,pp,gg)
        int w = tid - 256;
        int d = w >> 2, pp = (w >> 1) & 1, gg = w & 1;
        float e[8]; float s = 0.f;
#pragma unroll
        for (int c = 0; c < 8; ++c) { e[c] = expf(lA[c * 64 + d * 8 + pp * 4 + g0 + gg]); s += e[c]; }
        float inv = 1.f / s;
#pragma unroll
        for (int c = 0; c < 8; ++c) sA[gg * 128 + pp * 64 + c * 8 + d] = e[c] * inv;
    } else if (tid < 292) {
        int w = tid - 288; int pp = w >> 1, gg = w & 1;
        float e[8]; float s = 0.f;
#pragma unroll
        for (int c = 0; c < 8; ++c) { e[c] = expf(lPi[c * 8 + pp * 4 + g0 + gg]); s += e[c]; }
        float inv = 1.f / s;
#pragma unroll
        for (int c = 0; c < 8; ++c) sPi[gg * 16 + pp * 8 + c] = e[c] * inv;
    } else if (tid < 294) {
        int gg = tid - 292;
        float e0 = expf(lSP[g0 + gg]), e1 = expf(lSP[4 + g0 + gg]);
        float inv = 1.f / (e0 + e1);
        sSP[gg * 2] = e0 * inv; sSP[gg * 2 + 1] = e1 * inv;
    }
    __syncthreads();

    // Bm normalize
#pragma unroll
    for (int k = 0; k < 8; ++k) {
        int w = tid + k * NTHREADS;
        sBm[w] *= sInv[((w >> 11) << 3) + (w & 7)];
    }
    __syncthreads();

    // ---------- register tables (reloaded per phase) ----------
    float A0r[64], A1r[64], Pi0r[8], Pi1r[8];
    float SP0, SP1;
    auto loadTabs = [&](int gg) {
        const float4* a0 = (const float4*)(sA + gg * 128);
        const float4* a1 = (const float4*)(sA + gg * 128 + 64);
#pragma unroll
        for (int q = 0; q < 16; ++q) {
            float4 v0 = a0[q];
            A0r[4*q] = v0.x; A0r[4*q+1] = v0.y; A0r[4*q+2] = v0.z; A0r[4*q+3] = v0.w;
            float4 v1 = a1[q];
            A1r[4*q] = v1.x; A1r[4*q+1] = v1.y; A1r[4*q+2] = v1.z; A1r[4*q+3] = v1.w;
        }
#pragma unroll
        for (int c = 0; c < 8; ++c) { Pi0r[c] = sPi[gg*16 + c]; Pi1r[c] = sPi[gg*16 + 8 + c]; }
        SP0 = sSP[gg*2]; SP1 = sSP[gg*2 + 1];
    };

    // acc[c] += scale * (A_pv . b), register-only with per-lane pv select
    auto matvec_acc = [&](const float* b, int pv, float scale, float* acc) {
        float s0[8], s1[8];
#pragma unroll
        for (int c = 0; c < 8; ++c) { s0[c] = 0.f; s1[c] = 0.f; }
#pragma unroll
        for (int c = 0; c < 8; ++c) {
#pragma unroll
            for (int d = 0; d < 8; ++d) {
                s0[c] += A0r[(c << 3) + d] * b[d];
                s1[c] += A1r[(c << 3) + d] * b[d];
            }
        }
#pragma unroll
        for (int c = 0; c < 8; ++c) acc[c] += scale * (pv ? s1[c] : s0[c]);
    };

    auto bm_gather = [&](int gg, int xv, float* bm) {
        const float4 v0 = *(const float4*)(sBm + (gg << 11) + (xv << 3));
        const float4 v1 = *(const float4*)(sBm + (gg << 11) + (xv << 3) + 4);
        bm[0] = v0.x; bm[1] = v0.y; bm[2] = v0.z; bm[3] = v0.w;
        bm[4] = v1.x; bm[5] = v1.y; bm[6] = v1.z; bm[7] = v1.w;
    };

    float ll0 = 0.f, ll1 = 0.f;   // log2-domain partials for g0, g0+1

    // ---------- stage 1: fused levels 11,10,9 (gg-loop, NOT unrolled) ----------
    {
        const int j = tid;   // level-9 node within tree
        const int4 pv4 = *(const int4*)(pos + 262016 + t * 2048 + 4 * j);
        const int4 xv4 = *(const int4*)(xx  + 262016 + t * 2048 + 4 * j);
        const int2 pu2 = *(const int2*)(pos + 130944 + t * 1024 + 2 * j);
        const int2 xu2 = *(const int2*)(xx  + 130944 + t * 1024 + 2 * j);
        const int xq = xx[65408 + t * 512 + j];

#pragma unroll 1
        for (int gg = 0; gg < 2; ++gg) {
            loadTabs(gg);
            float llacc = 0.f;
            float tq[8] = {0,0,0,0,0,0,0,0};
#pragma unroll
            for (int u = 0; u < 2; ++u) {
                float tu[8] = {0,0,0,0,0,0,0,0};
#pragma unroll
                for (int v = 0; v < 2; ++v) {
                    const int k = 2 * u + v;
                    const int pv  = (k == 0) ? pv4.x : (k == 1) ? pv4.y : (k == 2) ? pv4.z : pv4.w;
                    const int xvv = (k == 0) ? xv4.x : (k == 1) ? xv4.y : (k == 2) ? xv4.z : xv4.w;
                    float bm[8]; bm_gather(gg, xvv, bm);
                    float b[8]; float nu = 0.f;
#pragma unroll
                    for (int c = 0; c < 8; ++c) {
                        b[c] = (pv ? Pi1r[c] : Pi0r[c]) * bm[c];
                        nu += b[c];
                    }
                    llacc += __log2f(nu);
                    matvec_acc(b, pv, (pv ? SP1 : SP0) / nu, tu);
                }
                const int pu = u ? pu2.y : pu2.x;
                const int xu = u ? xu2.y : xu2.x;
                float bm[8]; bm_gather(gg, xu, bm);
                float bu[8]; float nuu = 0.f;
#pragma unroll
                for (int c = 0; c < 8; ++c) { bu[c] = tu[c] * bm[c]; nuu += bu[c]; }
                llacc += __log2f(nuu);
                matvec_acc(bu, pu, (pu ? SP1 : SP0) / nuu, tq);
            }
            float bm[8]; bm_gather(gg, xq, bm);
            float bq[8]; float nuq = 0.f;
#pragma unroll
            for (int c = 0; c < 8; ++c) { bq[c] = tq[c] * bm[c]; nuq += bq[c]; }
            llacc += __log2f(nuq);
            const float inv = 1.f / nuq;
#pragma unroll
            for (int c = 0; c < 8; ++c) buf0[j * NSTR + (gg << 3) + c] = bq[c] * inv;
            if (gg == 0) ll0 += llacc; else ll1 += llacc;
        }
    }
    __syncthreads();

    // ---------- stage 2: both gi concurrent, 2 levels per barrier ----------
    const int mygi = tid >> 8;      // wave-uniform
    const int q    = tid & 255;
    loadTabs(mygi);
    float llt = 0.f;                // own-gi stage-2 partial (log2)

    // children level L in bin_ (within-tree idx 4q+i) -> parents level L-2 in bout_[q]
    auto step2 = [&](const float* bin_, float* bout_, int L) {
        const int nQ = 1 << (L - 2);
        if (q < nQ) {
            const int offC = 128 * ((1 << L) - 1) + t * (1 << L);
            const int offM = 128 * ((1 << (L - 1)) - 1) + t * (1 << (L - 1));
            const int offP = 128 * ((1 << (L - 2)) - 1) + t * (1 << (L - 2));
            const int4 pc = *(const int4*)(pos + offC + 4 * q);
            const int2 pm = *(const int2*)(pos + offM + 2 * q);
            const int2 xm = *(const int2*)(xx  + offM + 2 * q);
            const int xp  = xx[offP + q];
            float tq8[8] = {0,0,0,0,0,0,0,0};
#pragma unroll
            for (int u = 0; u < 2; ++u) {
                float tu8[8] = {0,0,0,0,0,0,0,0};
#pragma unroll
                for (int v = 0; v < 2; ++v) {
                    const int i = 2 * u + v;
                    const int pvc = (i == 0) ? pc.x : (i == 1) ? pc.y : (i == 2) ? pc.z : pc.w;
                    const float* bp = &bin_[(4 * q + i) * NSTR + (mygi << 3)];
                    float b[8];
#pragma unroll
                    for (int d = 0; d < 8; ++d) b[d] = bp[d];
                    matvec_acc(b, pvc, pvc ? SP1 : SP0, tu8);
                }
                const int pmu = u ? pm.y : pm.x;
                const int xmu = u ? xm.y : xm.x;
                float bm[8]; bm_gather(mygi, xmu, bm);
                float bu[8]; float nu = 0.f;
#pragma unroll
                for (int c = 0; c < 8; ++c) { bu[c] = tu8[c] * bm[c]; nu += bu[c]; }
                llt += __log2f(nu);
                matvec_acc(bu, pmu, (pmu ? SP1 : SP0) / nu, tq8);
            }
            float bm[8]; bm_gather(mygi, xp, bm);
            float bp8[8]; float nu = 0.f;
#pragma unroll
            for (int c = 0; c < 8; ++c) { bp8[c] = tq8[c] * bm[c]; nu += bp8[c]; }
            llt += __log2f(nu);
            const float inv = 1.f / nu;
#pragma unroll
            for (int c = 0; c < 8; ++c) bout_[q * NSTR + (mygi << 3) + c] = bp8[c] * inv;
        }
        __syncthreads();
    };

    step2(buf0, buf1, 9);   // level 9 -> 7   (q < 128)
    step2(buf1, buf0, 7);   // level 7 -> 5   (q < 32)
    step2(buf0, buf1, 5);   // level 5 -> 3   (q < 8)

    // final: levels 3 -> 2 -> 1 -> 0 in one thread per gi (q == 0)
    if (q == 0) {
        const int off3 = 896 + t * 8;
        const int off2 = 384 + t * 4;
        const int off1 = 128 + t * 2;
        const int4 p3a = *(const int4*)(pos + off3);
        const int4 p3b = *(const int4*)(pos + off3 + 4);
        const int4 p2  = *(const int4*)(pos + off2);
        const int4 x2  = *(const int4*)(xx  + off2);
        const int2 p1  = *(const int2*)(pos + off1);
        const int2 x1  = *(const int2*)(xx  + off1);
        const int x0   = xx[t];

        float tl1a[8] = {0,0,0,0,0,0,0,0};
        float tl1b[8] = {0,0,0,0,0,0,0,0};
#pragma unroll
        for (int w = 0; w < 4; ++w) {
            float tw[8] = {0,0,0,0,0,0,0,0};
#pragma unroll
            for (int v = 0; v < 2; ++v) {
                const int i = 2 * w + v;
                const int pvc = (i == 0) ? p3a.x : (i == 1) ? p3a.y : (i == 2) ? p3a.z :
                                (i == 3) ? p3a.w : (i == 4) ? p3b.x : (i == 5) ? p3b.y :
                                (i == 6) ? p3b.z : p3b.w;
                const float* bp = &buf1[i * NSTR + (mygi << 3)];
                float b[8];
#pragma unroll
                for (int d = 0; d < 8; ++d) b[d] = bp[d];
                matvec_acc(b, pvc, pvc ? SP1 : SP0, tw);
            }
            const int pw = (w == 0) ? p2.x : (w == 1) ? p2.y : (w == 2) ? p2.z : p2.w;
            const int xw = (w == 0) ? x2.x : (w == 1) ? x2.y : (w == 2) ? x2.z : x2.w;
            float bm[8]; bm_gather(mygi, xw, bm);
            float bw[8]; float nu = 0.f;
#pragma unroll
            for (int c = 0; c < 8; ++c) { bw[c] = tw[c] * bm[c]; nu += bw[c]; }
            llt += __log2f(nu);
            matvec_acc(bw, pw, (pw ? SP1 : SP0) / nu, (w < 2) ? tl1a : tl1b);
        }
        float tl0[8] = {0,0,0,0,0,0,0,0};
#pragma unroll
        for (int u = 0; u < 2; ++u) {
            const float* tsrc = u ? tl1b : tl1a;
            const int pu = u ? p1.y : p1.x;
            const int xu = u ? x1.y : x1.x;
            float bm[8]; bm_gather(mygi, xu, bm);
            float bu[8]; float nu = 0.f;
#pragma unroll
            for (int c = 0; c < 8; ++c) { bu[c] = tsrc[c] * bm[c]; nu += bu[c]; }
            llt += __log2f(nu);
            matvec_acc(bu, pu, (pu ? SP1 : SP0) / nu, tl0);
        }
        float bm[8]; bm_gather(mygi, x0, bm);
        float nu = 0.f;
#pragma unroll
        for (int c = 0; c < 8; ++c) nu += tl0[c] * bm[c];
        llt += __log2f(nu);
    }
    if (mygi) ll1 += llt; else ll0 += llt;

    // ---------- final log-likelihood reduction ----------
    float f0 = ll0 * 0.69314718055994530942f;   // log2 -> ln
    float f1 = ll1 * 0.69314718055994530942f;
#pragma unroll
    for (int o = 32; o >= 1; o >>= 1) {
        f0 += __shfl_xor(f0, o, 64);
        f1 += __shfl_xor(f1, o, 64);
    }
    if ((tid & 63) == 0) {
        atomicAdd(&sLL[0], (double)f0);
        atomicAdd(&sLL[1], (double)f1);
    }
    __syncthreads();
    if (tid < 2) out[(t << 2) + g0 + tid] = (float)sLL[tid];
}

extern "C" void kernel_launch(void* const* d_in, const int* in_sizes, int n_in,
                              void* d_out, int out_size, void* d_ws, size_t ws_size,
                              hipStream_t stream) {
    const float* lA  = (const float*)d_in[0];
    const float* lB  = (const float*)d_in[1];
    const float* lPi = (const float*)d_in[2];
    const float* lSP = (const float*)d_in[3];
    const int*   pos = (const int*)d_in[4];
    const int*   xv  = (const int*)d_in[5];
    float* out = (float*)d_out;
    htmm_kernel<<<256, NTHREADS, 0, stream>>>(lA, lB, lPi, lSP, pos, xv, out);
}

// Round 8
// 104.434 us; speedup vs baseline: 1.0340x; 1.0071x over previous
//
#include <hip/hip_runtime.h>
#include <math.h>

// HiddenTreeMarkovModel upward recursion.
// T_TREES=128, BR=2, DEPTH=11, C=8, L=2, M=256, G=4.
// Grid = 256 blocks (one resident block per CU, single pass):
//   block = (tree t, g-pair), t = blockIdx.x>>1, g0 = 2*(blockIdx.x&1).
// 512 threads = 8 waves = 2 waves/SIMD.
//
// Round-8 fix: the VGPR cap is set by the backend's LDS-derived occupancy
// target, not by waves_per_eu attributes (r3: 70KB LDS -> 2WG -> 8 waves/EU
// -> 64 VGPR; r6/r7: 60KB -> 2WG -> 4 waves/EU -> 128 VGPR; both spilled the
// ~210-reg working set -> 29MB scratch writes/dispatch). Fix: widen the beta
// buffers (NSTR 17->27, still odd so writes stay 2-lanes/bank = free) so
// LDS = 86752 B > 80KB -> only ONE 512-thread WG fits per CU -> compiler
// targets 2 waves/EU -> 256-VGPR budget -> A matrices stay in registers,
// zero spill. Runtime occupancy unchanged (grid 256 = 1 WG/CU regardless).
// Math identical to rounds 6/7 (passed, absmax 0.0).
//
// Stage 1: fused levels 11,10,9 (7-node subtree in registers), gg-loop
//          (unroll 1: one g's tables live at a time).
// Stage 2: both gi's concurrent (thread=(mygi,q)); two tree levels fused per
//          barrier: 9->7->5->3, then 3->0 in one thread. 4 barriers total.
// Level offsets: offs[l] = 128*(2^l - 1); tree t owns [offs[l]+t*2^l, +2^l).

#define NTHREADS 512
#define NSTR 27   // per-node floats in beta buffers: 2 gi x 8 c + pad.
                  // Odd => node-stride writes hit 2 lanes/bank (free).
                  // 27 (not 17) pushes LDS past 80KB: 1 WG/CU -> 256-VGPR cap.

__global__ __launch_bounds__(NTHREADS)
__attribute__((amdgpu_waves_per_eu(2, 2)))
void htmm_kernel(
    const float* __restrict__ lA,   // (C,C,L,G)  c*64 + d*8 + p*4 + g
    const float* __restrict__ lB,   // (C,M,G)    c*1024 + m*4 + g
    const float* __restrict__ lPi,  // (C,L,G)    c*8 + p*4 + g
    const float* __restrict__ lSP,  // (L,G)      p*4 + g
    const int* __restrict__ pos,
    const int* __restrict__ xx,
    float* __restrict__ out)        // (128,4)
{
    __shared__ __align__(16) float sBm[2 * 256 * 8];  // [gg][m][c]      16384 B
    __shared__ __align__(16) float sA[256];           // [gg][pv][c][d]   1024 B
    __shared__ __align__(16) float sPi[32];           // [gg][pv][c]       128 B
    __shared__ float sSP[4];                          // [gg*2+pv]
    __shared__ float sInv[16];                        // [gg*8+c]
    __shared__ float buf0[512 * NSTR];                // levels 9, 5     55296 B
    __shared__ float buf1[128 * NSTR];                // levels 7, 3     13824 B
    __shared__ double sLL[2];
    // total ~86.8 KB > 80 KB => 1 WG/CU => 256-VGPR register budget

    const int tid = threadIdx.x;
    const int t  = blockIdx.x >> 1;
    const int g0 = (blockIdx.x & 1) << 1;

    if (tid < 2) sLL[tid] = 0.0;

    // ---------- softmax tables (our 2 g's) ----------
    // Bm exp pass: 4096 elems, layout [gg][m][c]
#pragma unroll
    for (int k = 0; k < 8; ++k) {
        int w = tid + k * NTHREADS;
        int gg = w >> 11, m = (w >> 3) & 255, c = w & 7;
        sBm[w] = expf(lB[c * 1024 + m * 4 + g0 + gg]);
    }
    __syncthreads();

    if (tid < 256) {
        // row sums over m per (gg,c): 16 rows x 16 threads, staggered
        int r = tid >> 4, seg = tid & 15;       // r = gg*8 + c
        int gg = r >> 3, c = r & 7;
        float s = 0.f;
#pragma unroll
        for (int i = 0; i < 16; ++i)
            s += sBm[(gg << 11) + (((seg * 16 + ((i + seg) & 15))) << 3) + c];
#pragma unroll
        for (int o = 8; o >= 1; o >>= 1) s += __shfl_xor(s, o, 64);
        if (seg == 0) sInv[r] = 1.0f / s;
    } else if (tid < 288) {
        // A softmax over c, per (d,pp,gg)
        int w = tid - 256;
        int d = w >> 2, pp = (w >> 1) & 1, gg = w & 1;
        float e[8]; float s = 0.f;
#pragma unroll
        for (int c = 0; c < 8; ++c) { e[c] = expf(lA[c * 64 + d * 8 + pp * 4 + g0 + gg]); s += e[c]; }
        float inv = 1.f / s;
#pragma unroll
        for (int c = 0; c < 8; ++c) sA[gg * 128 + pp * 64 + c * 8 + d] = e[c] * inv;
    } else if (tid < 292) {
        int w = tid - 288; int pp = w >> 1, gg = w & 1;
        float e[8]; float s = 0.f;
#pragma unroll
        for (int c = 0; c < 8; ++c) { e[c] = expf(lPi[c * 8 + pp * 4 + g0 + gg]); s += e[c]; }
        float inv = 1.f / s;
#pragma unroll
        for (int c = 0; c < 8; ++c) sPi[gg * 16 + pp * 8 + c] = e[c] * inv;
    } else if (tid < 294) {
        int gg = tid - 292;
        float e0 = expf(lSP[g0 + gg]), e1 = expf(lSP[4 + g0 + gg]);
        float inv = 1.f / (e0 + e1);
        sSP[gg * 2] = e0 * inv; sSP[gg * 2 + 1] = e1 * inv;
    }
    __syncthreads();

    // Bm normalize
#pragma unroll
    for (int k = 0; k < 8; ++k) {
        int w = tid + k * NTHREADS;
        sBm[w] *= sInv[((w >> 11) << 3) + (w & 7)];
    }
    __syncthreads();

    // ---------- register tables (reloaded per phase) ----------
    float A0r[64], A1r[64], Pi0r[8], Pi1r[8];
    float SP0, SP1;
    auto loadTabs = [&](int gg) {
        const float4* a0 = (const float4*)(sA + gg * 128);
        const float4* a1 = (const float4*)(sA + gg * 128 + 64);
#pragma unroll
        for (int q = 0; q < 16; ++q) {
            float4 v0 = a0[q];
            A0r[4*q] = v0.x; A0r[4*q+1] = v0.y; A0r[4*q+2] = v0.z; A0r[4*q+3] = v0.w;
            float4 v1 = a1[q];
            A1r[4*q] = v1.x; A1r[4*q+1] = v1.y; A1r[4*q+2] = v1.z; A1r[4*q+3] = v1.w;
        }
#pragma unroll
        for (int c = 0; c < 8; ++c) { Pi0r[c] = sPi[gg*16 + c]; Pi1r[c] = sPi[gg*16 + 8 + c]; }
        SP0 = sSP[gg*2]; SP1 = sSP[gg*2 + 1];
    };

    // acc[c] += scale * (A_pv . b), register-only with per-lane pv select
    auto matvec_acc = [&](const float* b, int pv, float scale, float* acc) {
        float s0[8], s1[8];
#pragma unroll
        for (int c = 0; c < 8; ++c) { s0[c] = 0.f; s1[c] = 0.f; }
#pragma unroll
        for (int c = 0; c < 8; ++c) {
#pragma unroll
            for (int d = 0; d < 8; ++d) {
                s0[c] += A0r[(c << 3) + d] * b[d];
                s1[c] += A1r[(c << 3) + d] * b[d];
            }
        }
#pragma unroll
        for (int c = 0; c < 8; ++c) acc[c] += scale * (pv ? s1[c] : s0[c]);
    };

    auto bm_gather = [&](int gg, int xv, float* bm) {
        const float4 v0 = *(const float4*)(sBm + (gg << 11) + (xv << 3));
        const float4 v1 = *(const float4*)(sBm + (gg << 11) + (xv << 3) + 4);
        bm[0] = v0.x; bm[1] = v0.y; bm[2] = v0.z; bm[3] = v0.w;
        bm[4] = v1.x; bm[5] = v1.y; bm[6] = v1.z; bm[7] = v1.w;
    };

    float ll0 = 0.f, ll1 = 0.f;   // log2-domain partials for g0, g0+1

    // ---------- stage 1: fused levels 11,10,9 (gg-loop, NOT unrolled) ----------
    {
        const int j = tid;   // level-9 node within tree
        const int4 pv4 = *(const int4*)(pos + 262016 + t * 2048 + 4 * j);
        const int4 xv4 = *(const int4*)(xx  + 262016 + t * 2048 + 4 * j);
        const int2 pu2 = *(const int2*)(pos + 130944 + t * 1024 + 2 * j);
        const int2 xu2 = *(const int2*)(xx  + 130944 + t * 1024 + 2 * j);
        const int xq = xx[65408 + t * 512 + j];

#pragma unroll 1
        for (int gg = 0; gg < 2; ++gg) {
            loadTabs(gg);
            float llacc = 0.f;
            float tq[8] = {0,0,0,0,0,0,0,0};
#pragma unroll
            for (int u = 0; u < 2; ++u) {
                float tu[8] = {0,0,0,0,0,0,0,0};
#pragma unroll
                for (int v = 0; v < 2; ++v) {
                    const int k = 2 * u + v;
                    const int pv  = (k == 0) ? pv4.x : (k == 1) ? pv4.y : (k == 2) ? pv4.z : pv4.w;
                    const int xvv = (k == 0) ? xv4.x : (k == 1) ? xv4.y : (k == 2) ? xv4.z : xv4.w;
                    float bm[8]; bm_gather(gg, xvv, bm);
                    float b[8]; float nu = 0.f;
#pragma unroll
                    for (int c = 0; c < 8; ++c) {
                        b[c] = (pv ? Pi1r[c] : Pi0r[c]) * bm[c];
                        nu += b[c];
                    }
                    llacc += __log2f(nu);
                    matvec_acc(b, pv, (pv ? SP1 : SP0) / nu, tu);
                }
                const int pu = u ? pu2.y : pu2.x;
                const int xu = u ? xu2.y : xu2.x;
                float bm[8]; bm_gather(gg, xu, bm);
                float bu[8]; float nuu = 0.f;
#pragma unroll
                for (int c = 0; c < 8; ++c) { bu[c] = tu[c] * bm[c]; nuu += bu[c]; }
                llacc += __log2f(nuu);
                matvec_acc(bu, pu, (pu ? SP1 : SP0) / nuu, tq);
            }
            float bm[8]; bm_gather(gg, xq, bm);
            float bq[8]; float nuq = 0.f;
#pragma unroll
            for (int c = 0; c < 8; ++c) { bq[c] = tq[c] * bm[c]; nuq += bq[c]; }
            llacc += __log2f(nuq);
            const float inv = 1.f / nuq;
#pragma unroll
            for (int c = 0; c < 8; ++c) buf0[j * NSTR + (gg << 3) + c] = bq[c] * inv;
            if (gg == 0) ll0 += llacc; else ll1 += llacc;
        }
    }
    __syncthreads();

    // ---------- stage 2: both gi concurrent, 2 levels per barrier ----------
    const int mygi = tid >> 8;      // wave-uniform
    const int q    = tid & 255;
    loadTabs(mygi);
    float llt = 0.f;                // own-gi stage-2 partial (log2)

    // children level L in bin_ (within-tree idx 4q+i) -> parents level L-2 in bout_[q]
    auto step2 = [&](const float* bin_, float* bout_, int L) {
        const int nQ = 1 << (L - 2);
        if (q < nQ) {
            const int offC = 128 * ((1 << L) - 1) + t * (1 << L);
            const int offM = 128 * ((1 << (L - 1)) - 1) + t * (1 << (L - 1));
            const int offP = 128 * ((1 << (L - 2)) - 1) + t * (1 << (L - 2));
            const int4 pc = *(const int4*)(pos + offC + 4 * q);
            const int2 pm = *(const int2*)(pos + offM + 2 * q);
            const int2 xm = *(const int2*)(xx  + offM + 2 * q);
            const int xp  = xx[offP + q];
            float tq8[8] = {0,0,0,0,0,0,0,0};
#pragma unroll
            for (int u = 0; u < 2; ++u) {
                float tu8[8] = {0,0,0,0,0,0,0,0};
#pragma unroll
                for (int v = 0; v < 2; ++v) {
                    const int i = 2 * u + v;
                    const int pvc = (i == 0) ? pc.x : (i == 1) ? pc.y : (i == 2) ? pc.z : pc.w;
                    const float* bp = &bin_[(4 * q + i) * NSTR + (mygi << 3)];
                    float b[8];
#pragma unroll
                    for (int d = 0; d < 8; ++d) b[d] = bp[d];
                    matvec_acc(b, pvc, pvc ? SP1 : SP0, tu8);
                }
                const int pmu = u ? pm.y : pm.x;
                const int xmu = u ? xm.y : xm.x;
                float bm[8]; bm_gather(mygi, xmu, bm);
                float bu[8]; float nu = 0.f;
#pragma unroll
                for (int c = 0; c < 8; ++c) { bu[c] = tu8[c] * bm[c]; nu += bu[c]; }
                llt += __log2f(nu);
                matvec_acc(bu, pmu, (pmu ? SP1 : SP0) / nu, tq8);
            }
            float bm[8]; bm_gather(mygi, xp, bm);
            float bp8[8]; float nu = 0.f;
#pragma unroll
            for (int c = 0; c < 8; ++c) { bp8[c] = tq8[c] * bm[c]; nu += bp8[c]; }
            llt += __log2f(nu);
            const float inv = 1.f / nu;
#pragma unroll
            for (int c = 0; c < 8; ++c) bout_[q * NSTR + (mygi << 3) + c] = bp8[c] * inv;
        }
        __syncthreads();
    };

    step2(buf0, buf1, 9);   // level 9 -> 7   (q < 128)
    step2(buf1, buf0, 7);   // level 7 -> 5   (q < 32)
    step2(buf0, buf1, 5);   // level 5 -> 3   (q < 8)

    // final: levels 3 -> 2 -> 1 -> 0 in one thread per gi (q == 0)
    if (q == 0) {
        const int off3 = 896 + t * 8;
        const int off2 = 384 + t * 4;
        const int off1 = 128 + t * 2;
        const int4 p3a = *(const int4*)(pos + off3);
        const int4 p3b = *(const int4*)(pos + off3 + 4);
        const int4 p2  = *(const int4*)(pos + off2);
        const int4 x2  = *(const int4*)(xx  + off2);
        const int2 p1  = *(const int2*)(pos + off1);
        const int2 x1  = *(const int2*)(xx  + off1);
        const int x0   = xx[t];

        float tl1a[8] = {0,0,0,0,0,0,0,0};
        float tl1b[8] = {0,0,0,0,0,0,0,0};
#pragma unroll
        for (int w = 0; w < 4; ++w) {
            float tw[8] = {0,0,0,0,0,0,0,0};
#pragma unroll
            for (int v = 0; v < 2; ++v) {
                const int i = 2 * w + v;
                const int pvc = (i == 0) ? p3a.x : (i == 1) ? p3a.y : (i == 2) ? p3a.z :
                                (i == 3) ? p3a.w : (i == 4) ? p3b.x : (i == 5) ? p3b.y :
                                (i == 6) ? p3b.z : p3b.w;
                const float* bp = &buf1[i * NSTR + (mygi << 3)];
                float b[8];
#pragma unroll
                for (int d = 0; d < 8; ++d) b[d] = bp[d];
                matvec_acc(b, pvc, pvc ? SP1 : SP0, tw);
            }
            const int pw = (w == 0) ? p2.x : (w == 1) ? p2.y : (w == 2) ? p2.z : p2.w;
            const int xw = (w == 0) ? x2.x : (w == 1) ? x2.y : (w == 2) ? x2.z : x2.w;
            float bm[8]; bm_gather(mygi, xw, bm);
            float bw[8]; float nu = 0.f;
#pragma unroll
            for (int c = 0; c < 8; ++c) { bw[c] = tw[c] * bm[c]; nu += bw[c]; }
            llt += __log2f(nu);
            matvec_acc(bw, pw, (pw ? SP1 : SP0) / nu, (w < 2) ? tl1a : tl1b);
        }
        float tl0[8] = {0,0,0,0,0,0,0,0};
#pragma unroll
        for (int u = 0; u < 2; ++u) {
            const float* tsrc = u ? tl1b : tl1a;
            const int pu = u ? p1.y : p1.x;
            const int xu = u ? x1.y : x1.x;
            float bm[8]; bm_gather(mygi, xu, bm);
            float bu[8]; float nu = 0.f;
#pragma unroll
            for (int c = 0; c < 8; ++c) { bu[c] = tsrc[c] * bm[c]; nu += bu[c]; }
            llt += __log2f(nu);
            matvec_acc(bu, pu, (pu ? SP1 : SP0) / nu, tl0);
        }
        float bm[8]; bm_gather(mygi, x0, bm);
        float nu = 0.f;
#pragma unroll
        for (int c = 0; c < 8; ++c) nu += tl0[c] * bm[c];
        llt += __log2f(nu);
    }
    if (mygi) ll1 += llt; else ll0 += llt;

    // ---------- final log-likelihood reduction ----------
    float f0 = ll0 * 0.69314718055994530942f;   // log2 -> ln
    float f1 = ll1 * 0.69314718055994530942f;
#pragma unroll
    for (int o = 32; o >= 1; o >>= 1) {
        f0 += __shfl_xor(f0, o, 64);
        f1 += __shfl_xor(f1, o, 64);
    }
    if ((tid & 63) == 0) {
        atomicAdd(&sLL[0], (double)f0);
        atomicAdd(&sLL[1], (double)f1);
    }
    __syncthreads();
    if (tid < 2) out[(t << 2) + g0 + tid] = (float)sLL[tid];
}

extern "C" void kernel_launch(void* const* d_in, const int* in_sizes, int n_in,
                              void* d_out, int out_size, void* d_ws, size_t ws_size,
                              hipStream_t stream) {
    const float* lA  = (const float*)d_in[0];
    const float* lB  = (const float*)d_in[1];
    const float* lPi = (const float*)d_in[2];
    const float* lSP = (const float*)d_in[3];
    const int*   pos = (const int*)d_in[4];
    const int*   xv  = (const int*)d_in[5];
    float* out = (float*)d_out;
    htmm_kernel<<<256, NTHREADS, 0, stream>>>(lA, lB, lPi, lSP, pos, xv, out);
}